// Round 1
// baseline (238.705 us; speedup 1.0000x reference)
//
#include <hip/hip_runtime.h>
#include <hip/hip_bf16.h>

typedef __bf16 bf16x8 __attribute__((ext_vector_type(8)));
typedef float f32x4 __attribute__((ext_vector_type(4)));
typedef unsigned short u16;
typedef u16 u16x8 __attribute__((ext_vector_type(8)));

#define DENSE_RC 0.0441941738f   // 1/sqrt(512)
#define CONV_RC  0.0147313913f   // 1/sqrt(9*512)

__device__ inline u16 f2bf(float v) {
  union { float f; unsigned u; } x; x.f = v;
  unsigned r = x.u + 0x7fffu + ((x.u >> 16) & 1u);   // RNE
  return (u16)(r >> 16);
}

__device__ inline void gload16(const void* g, void* l) {
  __builtin_amdgcn_global_load_lds(
      (const __attribute__((address_space(1))) unsigned int*)g,
      (__attribute__((address_space(3))) unsigned int*)l, 16, 0, 0);
}

// ---------- 1. style: s[b][i] = DENSE_RC * (y[b] . w_mod[:,i]) + b_mod[i] + 1
__global__ void style_k(const float* __restrict__ y, const float* __restrict__ wm,
                        const float* __restrict__ bm, float* __restrict__ s) {
  const int b = blockIdx.x >> 1;
  const int i = ((blockIdx.x & 1) << 8) + threadIdx.x;
  const float* yb = y + b * 512;
  float acc = 0.f;
#pragma unroll 8
  for (int j = 0; j < 512; ++j) acc += yb[j] * wm[j * 512 + i];
  s[b * 512 + i] = acc * DENSE_RC + bm[i] + 1.0f;
}

// ---------- 2. wsq[i][o] = sum_t w[t][i][o]^2
__global__ void wsq_k(const float* __restrict__ w, float* __restrict__ wsq) {
  const int idx = blockIdx.x * 256 + threadIdx.x;   // i*512+o
  float a = 0.f;
#pragma unroll
  for (int t = 0; t < 9; ++t) { float v = w[(size_t)t * 262144 + idx]; a += v * v; }
  wsq[idx] = a;
}

// ---------- 3. d[b][o] = rsqrt(CONV_RC^2 * sum_i s^2 * wsq + 1e-8)
__global__ void demod_k(const float* __restrict__ s, const float* __restrict__ wsq,
                        float* __restrict__ dmd) {
  const int b = blockIdx.x >> 1;
  const int o = ((blockIdx.x & 1) << 8) + threadIdx.x;
  const float* sb = s + b * 512;
  float a = 0.f;
#pragma unroll 4
  for (int i = 0; i < 512; ++i) { float sv = sb[i]; a += sv * sv * wsq[i * 512 + o]; }
  dmd[b * 512 + o] = rsqrtf(a * (CONV_RC * CONV_RC) + 1e-8f);
}

// ---------- 4. ww[b][t][o][i] = bf16( w[t][i][o] * CONV_RC * s[b][i] * d[b][o] )
__global__ void modw_k(const float* __restrict__ w, const float* __restrict__ s,
                       const float* __restrict__ dmd, u16* __restrict__ wwb) {
  const int blk = blockIdx.x;               // 9*16*8 = 1152
  const int ob = blk & 7, ib = (blk >> 3) & 15, t = blk >> 7;
  __shared__ float lw[32][65];
  const int tid = threadIdx.x;
#pragma unroll
  for (int k = 0; k < 8; ++k) {
    const int e = tid + k * 256;
    const int i = e >> 6, o = e & 63;
    lw[i][o] = w[(size_t)t * 262144 + (size_t)(ib * 32 + i) * 512 + ob * 64 + o];
  }
  __syncthreads();
  const int oo = tid >> 2, q = tid & 3;
  const int ii0 = q * 8;
  for (int b = 0; b < 8; ++b) {
    const float f = CONV_RC * dmd[b * 512 + ob * 64 + oo];
    u16x8 pk;
#pragma unroll
    for (int j = 0; j < 8; ++j)
      pk[j] = f2bf(lw[ii0 + j][oo] * s[b * 512 + ib * 32 + ii0 + j] * f);
    *(u16x8*)(wwb + ((size_t)(b * 9 + t) * 512 + ob * 64 + oo) * 512 + ib * 32 + ii0) = pk;
  }
}

// ---------- 5a. zero xpad
__global__ void zero_k(float4* __restrict__ p, int n) {
  const int stride = gridDim.x * blockDim.x;
  for (int i = blockIdx.x * blockDim.x + threadIdx.x; i < n; i += stride)
    p[i] = make_float4(0.f, 0.f, 0.f, 0.f);
}

// ---------- 5b. xpad[b][h+1][wcol+1][i] = bf16(x[b][i][h][wcol])   (NCHW -> padded NHWC)
__global__ void fill_k(const float* __restrict__ x, u16* __restrict__ xpad) {
  const int blk = blockIdx.x;               // 8*64*4 = 2048
  const int ib = blk & 3, hh = (blk >> 2) & 63, b = blk >> 8;
  __shared__ float lx[128][65];
  const int tid = threadIdx.x;
#pragma unroll
  for (int k = 0; k < 2; ++k) {
    const int u = tid + k * 256;
    const int i = u >> 2, w0 = (u & 3) * 16;
    const float* src = x + (size_t)((b * 512 + ib * 128 + i) * 64 + hh) * 64 + w0;
    float tmp[16];
    ((float4*)tmp)[0] = ((const float4*)src)[0];
    ((float4*)tmp)[1] = ((const float4*)src)[1];
    ((float4*)tmp)[2] = ((const float4*)src)[2];
    ((float4*)tmp)[3] = ((const float4*)src)[3];
#pragma unroll
    for (int j = 0; j < 16; ++j) lx[i][w0 + j] = tmp[j];
  }
  __syncthreads();
  const int c = tid >> 2, q = tid & 3;      // c: 0..63 col, q: i-subgroup
  const size_t base = ((size_t)(b * 66 + hh + 1) * 66 + (c + 1)) * 512 + ib * 128;
#pragma unroll
  for (int k = 0; k < 4; ++k) {
    const int irow = k * 32 + q * 8;
    u16x8 pk;
#pragma unroll
    for (int j = 0; j < 8; ++j) pk[j] = f2bf(lx[irow + j][c]);
    *(u16x8*)(xpad + base + irow) = pk;
  }
}

// ---------- 6. conv: out[b][o][h][w] = sum_{t,i} xpad[b][h+ty][w+tx][i] * ww[b][t][o][i]
// block: [64 o] x [4 rows x 64 px], 4 waves, wave = one output row, [64 o]x[64 px]
// LDS: WS [9][64][32] bf16 (36864B) + XS [6][66][32] bf16 (25344B) = 62208B
__global__ __launch_bounds__(256, 2) void conv_k(const u16* __restrict__ xpad,
                                                 const u16* __restrict__ wwb,
                                                 float* __restrict__ out) {
  __shared__ __align__(1024) char SM[62208];
  int blk = (int)blockIdx.x;
  blk = ((blk & 7) << 7) | (blk >> 3);      // XCD swizzle (1024 % 8 == 0, bijective)
  const int pt = blk & 15, ot = (blk >> 4) & 7, b = blk >> 7;
  const int tid = threadIdx.x;
  const int lane = tid & 63, wv = tid >> 6;
  const int rA = lane >> 4, cA = lane & 15;
  const int h0 = pt * 4;

  f32x4 acc[4][4];
#pragma unroll
  for (int i = 0; i < 4; ++i)
#pragma unroll
    for (int j = 0; j < 4; ++j) acc[i][j] = (f32x4){0.f, 0.f, 0.f, 0.f};

  const size_t wwbase = (size_t)(b * 9) * 262144 + (size_t)ot * 64 * 512;
  const size_t xbase  = (size_t)(b * 66 + h0) * (66 * 512);

  for (int kb = 0; kb < 16; ++kb) {
    const int i0 = kb * 32;
    // stage: 2304 chunks of WS (64-aligned region) then 1584 of XS
    for (int cc = tid; cc < 3888; cc += 256) {
      if (cc < 2304) {
        const int i8 = cc & 3, o = (cc >> 2) & 63, t = cc >> 8;
        gload16(wwb + wwbase + (size_t)t * 262144 + o * 512 + i0 + i8 * 8, SM + cc * 16);
      } else {
        const int c2 = cc - 2304;
        const int i8 = c2 & 3, rc = c2 >> 2;
        const int r = rc / 66, c = rc - r * 66;
        gload16(xpad + xbase + (size_t)(r * 66 + c) * 512 + i0 + i8 * 8,
                SM + 36864 + c2 * 16);
      }
    }
    asm volatile("s_waitcnt vmcnt(0)" ::: "memory");
    __syncthreads();

    const char* Ab = SM + cA * 64 + rA * 16;
    const char* Bb = SM + 36864 + (wv * 66 + cA) * 64 + rA * 16;
#pragma unroll
    for (int t = 0; t < 9; ++t) {
      const int ty = t / 3, tx = t % 3;
      bf16x8 af[4], bfr[4];
#pragma unroll
      for (int mi = 0; mi < 4; ++mi)
        af[mi] = *(const bf16x8*)(Ab + t * 4096 + mi * 1024);
#pragma unroll
      for (int ni = 0; ni < 4; ++ni)
        bfr[ni] = *(const bf16x8*)(Bb + (ty * 66 + tx) * 64 + ni * 1024);
#pragma unroll
      for (int mi = 0; mi < 4; ++mi)
#pragma unroll
        for (int ni = 0; ni < 4; ++ni)
          acc[mi][ni] = __builtin_amdgcn_mfma_f32_16x16x32_bf16(af[mi], bfr[ni],
                                                                acc[mi][ni], 0, 0, 0);
    }
    __syncthreads();
  }

  const int h = h0 + wv;
#pragma unroll
  for (int mi = 0; mi < 4; ++mi)
#pragma unroll
    for (int ni = 0; ni < 4; ++ni) {
      const int wc = ni * 16 + cA;
#pragma unroll
      for (int r = 0; r < 4; ++r) {
        const int o = ot * 64 + mi * 16 + rA * 4 + r;
        out[((size_t)(b * 512 + o) * 64 + h) * 64 + wc] = acc[mi][ni][r];
      }
    }
}

extern "C" void kernel_launch(void* const* d_in, const int* in_sizes, int n_in,
                              void* d_out, int out_size, void* d_ws, size_t ws_size,
                              hipStream_t stream) {
  const float* x     = (const float*)d_in[0];   // [8,512,64,64]
  const float* y     = (const float*)d_in[1];   // [8,512]
  const float* w     = (const float*)d_in[2];   // [3,3,512,512]
  const float* w_mod = (const float*)d_in[3];   // [512,512]
  const float* b_mod = (const float*)d_in[4];   // [512]
  float* out = (float*)d_out;

  char* ws = (char*)d_ws;
  float* s    = (float*)(ws);                               // 16 KB
  float* dmd  = (float*)(ws + 16384);                       // 16 KB
  float* wsq  = (float*)(ws + 32768);                       // 1 MB
  u16*   wwb  = (u16*)(ws + 32768 + 1048576);               // 37,748,736 B
  u16*   xpad = (u16*)(ws + 32768 + 1048576 + 37748736);    // 35,684,352 B

  style_k<<<16, 256, 0, stream>>>(y, w_mod, b_mod, s);
  wsq_k<<<1024, 256, 0, stream>>>(w, wsq);
  demod_k<<<16, 256, 0, stream>>>(s, wsq, dmd);
  modw_k<<<1152, 256, 0, stream>>>(w, s, dmd, wwb);
  zero_k<<<2048, 256, 0, stream>>>((float4*)xpad, 35684352 / 16);
  fill_k<<<2048, 256, 0, stream>>>(x, xpad);
  conv_k<<<1024, 256, 0, stream>>>(xpad, wwb, out);
}

// Round 2
// 216.875 us; speedup vs baseline: 1.1007x; 1.1007x over previous
//
#include <hip/hip_runtime.h>
#include <hip/hip_bf16.h>

typedef __bf16 bf16x8 __attribute__((ext_vector_type(8)));
typedef float f32x4 __attribute__((ext_vector_type(4)));
typedef unsigned short u16;
typedef u16 u16x8 __attribute__((ext_vector_type(8)));

#define DENSE_RC 0.0441941738f   // 1/sqrt(512)
#define CONV_RC  0.0147313913f   // 1/sqrt(9*512)

__device__ inline u16 f2bf(float v) {
  union { float f; unsigned u; } x; x.f = v;
  unsigned r = x.u + 0x7fffu + ((x.u >> 16) & 1u);   // RNE
  return (u16)(r >> 16);
}

__device__ inline void gload16(const void* g, void* l) {
  __builtin_amdgcn_global_load_lds(
      (const __attribute__((address_space(1))) unsigned int*)g,
      (__attribute__((address_space(3))) unsigned int*)l, 16, 0, 0);
}

// ---------- 1. style: s[b][i] = DENSE_RC * (y[b] . w_mod[:,i]) + b_mod[i] + 1
__global__ void style_k(const float* __restrict__ y, const float* __restrict__ wm,
                        const float* __restrict__ bm, float* __restrict__ s) {
  const int b = blockIdx.x >> 1;
  const int i = ((blockIdx.x & 1) << 8) + threadIdx.x;
  const float* yb = y + b * 512;
  float acc = 0.f;
#pragma unroll 8
  for (int j = 0; j < 512; ++j) acc += yb[j] * wm[j * 512 + i];
  s[b * 512 + i] = acc * DENSE_RC + bm[i] + 1.0f;
}

// ---------- 2. wsq[i][o] = sum_t w[t][i][o]^2
__global__ void wsq_k(const float* __restrict__ w, float* __restrict__ wsq) {
  const int idx = blockIdx.x * 256 + threadIdx.x;   // i*512+o
  float a = 0.f;
#pragma unroll
  for (int t = 0; t < 9; ++t) { float v = w[(size_t)t * 262144 + idx]; a += v * v; }
  wsq[idx] = a;
}

// ---------- 3. d[b][o] = rsqrt(CONV_RC^2 * sum_i s^2 * wsq + 1e-8)
__global__ void demod_k(const float* __restrict__ s, const float* __restrict__ wsq,
                        float* __restrict__ dmd) {
  const int b = blockIdx.x >> 1;
  const int o = ((blockIdx.x & 1) << 8) + threadIdx.x;
  const float* sb = s + b * 512;
  float a = 0.f;
#pragma unroll 4
  for (int i = 0; i < 512; ++i) { float sv = sb[i]; a += sv * sv * wsq[i * 512 + o]; }
  dmd[b * 512 + o] = rsqrtf(a * (CONV_RC * CONV_RC) + 1e-8f);
}

// ---------- 4. ww[b][t][o][i] = bf16( w[t][i][o] * CONV_RC * s[b][i] * d[b][o] )
__global__ void modw_k(const float* __restrict__ w, const float* __restrict__ s,
                       const float* __restrict__ dmd, u16* __restrict__ wwb) {
  const int blk = blockIdx.x;               // 9*16*8 = 1152
  const int ob = blk & 7, ib = (blk >> 3) & 15, t = blk >> 7;
  __shared__ float lw[32][65];
  const int tid = threadIdx.x;
#pragma unroll
  for (int k = 0; k < 8; ++k) {
    const int e = tid + k * 256;
    const int i = e >> 6, o = e & 63;
    lw[i][o] = w[(size_t)t * 262144 + (size_t)(ib * 32 + i) * 512 + ob * 64 + o];
  }
  __syncthreads();
  const int oo = tid >> 2, q = tid & 3;
  const int ii0 = q * 8;
  for (int b = 0; b < 8; ++b) {
    const float f = CONV_RC * dmd[b * 512 + ob * 64 + oo];
    u16x8 pk;
#pragma unroll
    for (int j = 0; j < 8; ++j)
      pk[j] = f2bf(lw[ii0 + j][oo] * s[b * 512 + ib * 32 + ii0 + j] * f);
    *(u16x8*)(wwb + ((size_t)(b * 9 + t) * 512 + ob * 64 + oo) * 512 + ib * 32 + ii0) = pk;
  }
}

// ---------- 5a. zero only the 1-px border ring of xpad
__global__ void border_k(u16* __restrict__ xpad) {
  const int idx = blockIdx.x * 256 + threadIdx.x;   // 520*256 = 133120 exact
  const int chunk = idx & 63;
  const int p = (idx >> 6) % 260;
  const int b = idx / (260 * 64);
  int row, col;
  if (p < 66)       { row = 0;       col = p; }
  else if (p < 132) { row = 65;      col = p - 66; }
  else if (p < 196) { row = p - 131; col = 0; }
  else              { row = p - 195; col = 65; }
  u16x8 z = {0, 0, 0, 0, 0, 0, 0, 0};
  *(u16x8*)(xpad + ((size_t)(b * 66 + row) * 66 + col) * 512 + chunk * 8) = z;
}

// ---------- 5b. xpad[b][h+1][wcol+1][i] = bf16(x[b][i][h][wcol])   (NCHW -> padded NHWC)
__global__ void fill_k(const float* __restrict__ x, u16* __restrict__ xpad) {
  const int blk = blockIdx.x;               // 8*64*4 = 2048
  const int ib = blk & 3, hh = (blk >> 2) & 63, b = blk >> 8;
  __shared__ float lx[128][65];
  const int tid = threadIdx.x;
#pragma unroll
  for (int k = 0; k < 2; ++k) {
    const int u = tid + k * 256;
    const int i = u >> 2, w0 = (u & 3) * 16;
    const float* src = x + (size_t)((b * 512 + ib * 128 + i) * 64 + hh) * 64 + w0;
    float tmp[16];
    ((float4*)tmp)[0] = ((const float4*)src)[0];
    ((float4*)tmp)[1] = ((const float4*)src)[1];
    ((float4*)tmp)[2] = ((const float4*)src)[2];
    ((float4*)tmp)[3] = ((const float4*)src)[3];
#pragma unroll
    for (int j = 0; j < 16; ++j) lx[i][w0 + j] = tmp[j];
  }
  __syncthreads();
  const int c = tid >> 2, q = tid & 3;      // c: 0..63 col, q: i-subgroup
  const size_t base = ((size_t)(b * 66 + hh + 1) * 66 + (c + 1)) * 512 + ib * 128;
#pragma unroll
  for (int k = 0; k < 4; ++k) {
    const int irow = k * 32 + q * 8;
    u16x8 pk;
#pragma unroll
    for (int j = 0; j < 8; ++j) pk[j] = f2bf(lx[irow + j][c]);
    *(u16x8*)(xpad + base + irow) = pk;
  }
}

// ---------- 6. conv: out[b][o][h][w] = sum_{t,i} xpad[b][h+ty][w+tx][i] * ww[b][t][o][i]
// block: [64 o] x [4 rows x 64 px], 4 waves, wave = one output row, [64 o]x[64 px]
// LDS: WS [9][64 o][2 x 16B-slot-swizzled] (36864B) + XS [6*66 rc][swz] (25344B)
// Swizzle (16B-chunk units, per region): phys = log ^ ((log>>3)&3)  — involution.
// Staging keeps LDS dest LINEAR (global_load_lds constraint) and pre-swizzles the
// GLOBAL source; fragment reads apply the same XOR. 8-way -> 2-way (free) conflicts.
__global__ __launch_bounds__(256, 2) void conv_k(const u16* __restrict__ xpad,
                                                 const u16* __restrict__ wwb,
                                                 float* __restrict__ out) {
  __shared__ __align__(1024) char SM[62208];
  int blk = (int)blockIdx.x;
  blk = ((blk & 7) << 7) | (blk >> 3);      // XCD swizzle (1024 % 8 == 0, bijective)
  const int pt = blk & 15, ot = (blk >> 4) & 7, b = blk >> 7;
  const int tid = threadIdx.x;
  const int lane = tid & 63, wv = tid >> 6;
  const int rA = lane >> 4, cA = lane & 15;
  const int h0 = pt * 4;

  const size_t wwbase = (size_t)(b * 9) * 262144 + (size_t)ot * 64 * 512;
  const size_t xbase  = (size_t)(b * 66 + h0) * (66 * 512);

  // -------- precompute per-thread staging pointers (advance 64B per kb) --------
  const u16* aw[9]; char* dw[9];
  const u16* ax[7]; char* dx[7];
#pragma unroll
  for (int r = 0; r < 9; ++r) {
    const int cc = tid + r * 256;                 // linear LDS dest chunk
    const int lc = cc ^ ((cc >> 3) & 3);          // logical chunk at this slot
    const int i8 = lc & 3, o = (lc >> 2) & 63, t = lc >> 8;
    aw[r] = wwb + wwbase + (size_t)t * 262144 + o * 512 + i8 * 8;
    dw[r] = SM + cc * 16;
  }
#pragma unroll
  for (int r = 0; r < 7; ++r) {
    const int c2 = tid + r * 256;
    const int lc = c2 ^ ((c2 >> 3) & 3);
    const int i8 = lc & 3, rc = lc >> 2;          // rc = row*66+col, offset is just rc*512
    ax[r] = xpad + xbase + (size_t)rc * 512 + i8 * 8;
    dx[r] = SM + 36864 + c2 * 16;
  }
  const bool extra = (tid < 48);                  // 1584 = 6*256 + 48

  f32x4 acc[4][4];
#pragma unroll
  for (int i = 0; i < 4; ++i)
#pragma unroll
    for (int j = 0; j < 4; ++j) acc[i][j] = (f32x4){0.f, 0.f, 0.f, 0.f};

  // A-read swizzle mask is lane-constant -> bake into base
  const char* Ab = SM + ((cA * 64 + rA * 16) ^ ((cA << 3) & 0x30));
  const int rc0 = wv * 66 + cA;

  for (int kb = 0; kb < 16; ++kb) {
#pragma unroll
    for (int r = 0; r < 9; ++r) gload16(aw[r], dw[r]);
#pragma unroll
    for (int r = 0; r < 6; ++r) gload16(ax[r], dx[r]);
    if (extra) gload16(ax[6], dx[6]);
    asm volatile("s_waitcnt vmcnt(0)" ::: "memory");
    __syncthreads();

#pragma unroll
    for (int t = 0; t < 9; ++t) {
      const int ty = t / 3, tx = t % 3;
      const int rct = rc0 + ty * 66 + tx;
      const char* Bt = SM + 36864 + ((rct * 64 + rA * 16) ^ ((rct << 3) & 0x30));
      bf16x8 af[4], bfr[4];
#pragma unroll
      for (int mi = 0; mi < 4; ++mi)
        af[mi] = *(const bf16x8*)(Ab + t * 4096 + mi * 1024);
#pragma unroll
      for (int ni = 0; ni < 4; ++ni)
        bfr[ni] = *(const bf16x8*)(Bt + ni * 1024);   // ni*1024 doesn't touch bits 4-5
#pragma unroll
      for (int mi = 0; mi < 4; ++mi)
#pragma unroll
        for (int ni = 0; ni < 4; ++ni)
          acc[mi][ni] = __builtin_amdgcn_mfma_f32_16x16x32_bf16(af[mi], bfr[ni],
                                                                acc[mi][ni], 0, 0, 0);
    }
    __syncthreads();

#pragma unroll
    for (int r = 0; r < 9; ++r) aw[r] += 32;      // +64B: next i-chunk
#pragma unroll
    for (int r = 0; r < 7; ++r) ax[r] += 32;
  }

  const int h = h0 + wv;
#pragma unroll
  for (int mi = 0; mi < 4; ++mi)
#pragma unroll
    for (int ni = 0; ni < 4; ++ni) {
      const int wc = ni * 16 + cA;
#pragma unroll
      for (int r = 0; r < 4; ++r) {
        const int o = ot * 64 + mi * 16 + rA * 4 + r;
        out[((size_t)(b * 512 + o) * 64 + h) * 64 + wc] = acc[mi][ni][r];
      }
    }
}

extern "C" void kernel_launch(void* const* d_in, const int* in_sizes, int n_in,
                              void* d_out, int out_size, void* d_ws, size_t ws_size,
                              hipStream_t stream) {
  const float* x     = (const float*)d_in[0];   // [8,512,64,64]
  const float* y     = (const float*)d_in[1];   // [8,512]
  const float* w     = (const float*)d_in[2];   // [3,3,512,512]
  const float* w_mod = (const float*)d_in[3];   // [512,512]
  const float* b_mod = (const float*)d_in[4];   // [512]
  float* out = (float*)d_out;

  char* ws = (char*)d_ws;
  float* s    = (float*)(ws);                               // 16 KB
  float* dmd  = (float*)(ws + 16384);                       // 16 KB
  float* wsq  = (float*)(ws + 32768);                       // 1 MB
  u16*   wwb  = (u16*)(ws + 32768 + 1048576);               // 37,748,736 B
  u16*   xpad = (u16*)(ws + 32768 + 1048576 + 37748736);    // 35,684,352 B

  style_k<<<16, 256, 0, stream>>>(y, w_mod, b_mod, s);
  wsq_k<<<1024, 256, 0, stream>>>(w, wsq);
  demod_k<<<16, 256, 0, stream>>>(s, wsq, dmd);
  modw_k<<<1152, 256, 0, stream>>>(w, s, dmd, wwb);
  border_k<<<520, 256, 0, stream>>>(xpad);
  fill_k<<<2048, 256, 0, stream>>>(x, xpad);
  conv_k<<<1024, 256, 0, stream>>>(xpad, wwb, out);
}

// Round 3
// 166.392 us; speedup vs baseline: 1.4346x; 1.3034x over previous
//
#include <hip/hip_runtime.h>
#include <hip/hip_bf16.h>

typedef __bf16 bf16x8 __attribute__((ext_vector_type(8)));
typedef float f32x4 __attribute__((ext_vector_type(4)));
typedef unsigned short u16;
typedef u16 u16x8 __attribute__((ext_vector_type(8)));

#define DENSE_RC 0.0441941738f   // 1/sqrt(512)
#define CONV_RC  0.0147313913f   // 1/sqrt(9*512)

__device__ inline u16 f2bf(float v) {
  union { float f; unsigned u; } x; x.f = v;
  unsigned r = x.u + 0x7fffu + ((x.u >> 16) & 1u);   // RNE
  return (u16)(r >> 16);
}

__device__ inline void gload16(const void* g, void* l) {
  __builtin_amdgcn_global_load_lds(
      (const __attribute__((address_space(1))) unsigned int*)g,
      (__attribute__((address_space(3))) unsigned int*)l, 16, 0, 0);
}

// ---------- 1. style: s[b][i] = DENSE_RC * (y[b] . w_mod[:,i]) + b_mod[i] + 1
// 64 blocks x 256 thr; block = 64 outputs, wave wv covers j-range [wv*128, wv*128+128)
__global__ void style_k(const float* __restrict__ y, const float* __restrict__ wm,
                        const float* __restrict__ bm, float* __restrict__ s) {
  const int tid = threadIdx.x, lane = tid & 63, wv = tid >> 6;
  const int idx = blockIdx.x * 64 + lane;         // 4096 outputs, 512-aligned per b
  const int b = idx >> 9, i = idx & 511;
  const float* yb = y + b * 512;
  float acc = 0.f;
  const int j0 = wv * 128;
#pragma unroll 8
  for (int j = j0; j < j0 + 128; ++j) acc += yb[j] * wm[j * 512 + i];
  __shared__ float red[4][64];
  red[wv][lane] = acc;
  __syncthreads();
  if (wv == 0) {
    float a = red[0][lane] + red[1][lane] + red[2][lane] + red[3][lane];
    s[idx] = a * DENSE_RC + bm[i] + 1.0f;
  }
}

// ---------- 2. wsq[i][o] = sum_t w[t][i][o]^2
__global__ void wsq_k(const float* __restrict__ w, float* __restrict__ wsq) {
  const int idx = blockIdx.x * 256 + threadIdx.x;   // i*512+o
  float a = 0.f;
#pragma unroll
  for (int t = 0; t < 9; ++t) { float v = w[(size_t)t * 262144 + idx]; a += v * v; }
  wsq[idx] = a;
}

// ---------- 3. d[b][o] = rsqrt(CONV_RC^2 * sum_i s^2 * wsq + 1e-8)
__global__ void demod_k(const float* __restrict__ s, const float* __restrict__ wsq,
                        float* __restrict__ dmd) {
  const int tid = threadIdx.x, lane = tid & 63, wv = tid >> 6;
  const int idx = blockIdx.x * 64 + lane;
  const int b = idx >> 9, o = idx & 511;
  const float* sb = s + b * 512;
  float a = 0.f;
  const int i0 = wv * 128;
#pragma unroll 4
  for (int i = i0; i < i0 + 128; ++i) { float sv = sb[i]; a += sv * sv * wsq[i * 512 + o]; }
  __shared__ float red[4][64];
  red[wv][lane] = a;
  __syncthreads();
  if (wv == 0) {
    float t = red[0][lane] + red[1][lane] + red[2][lane] + red[3][lane];
    dmd[idx] = rsqrtf(t * (CONV_RC * CONV_RC) + 1e-8f);
  }
}

// ---------- 4. ww[b][t][o][i] = bf16( w[t][i][o] * CONV_RC * s[b][i] * d[b][o] )
__global__ void modw_k(const float* __restrict__ w, const float* __restrict__ s,
                       const float* __restrict__ dmd, u16* __restrict__ wwb) {
  const int blk = blockIdx.x;               // 9*16*8 = 1152
  const int ob = blk & 7, ib = (blk >> 3) & 15, t = blk >> 7;
  __shared__ float lw[32][65];
  const int tid = threadIdx.x;
#pragma unroll
  for (int k = 0; k < 8; ++k) {
    const int e = tid + k * 256;
    const int i = e >> 6, o = e & 63;
    lw[i][o] = w[(size_t)t * 262144 + (size_t)(ib * 32 + i) * 512 + ob * 64 + o];
  }
  __syncthreads();
  const int oo = tid >> 2, q = tid & 3;
  const int ii0 = q * 8;
  for (int b = 0; b < 8; ++b) {
    const float f = CONV_RC * dmd[b * 512 + ob * 64 + oo];
    u16x8 pk;
#pragma unroll
    for (int j = 0; j < 8; ++j)
      pk[j] = f2bf(lw[ii0 + j][oo] * s[b * 512 + ib * 32 + ii0 + j] * f);
    *(u16x8*)(wwb + ((size_t)(b * 9 + t) * 512 + ob * 64 + oo) * 512 + ib * 32 + ii0) = pk;
  }
}

// ---------- 5a. zero only the 1-px border ring of xpad
__global__ void border_k(u16* __restrict__ xpad) {
  const int idx = blockIdx.x * 256 + threadIdx.x;   // 520*256 = 133120 exact
  const int chunk = idx & 63;
  const int p = (idx >> 6) % 260;
  const int b = idx / (260 * 64);
  int row, col;
  if (p < 66)       { row = 0;       col = p; }
  else if (p < 132) { row = 65;      col = p - 66; }
  else if (p < 196) { row = p - 131; col = 0; }
  else              { row = p - 195; col = 65; }
  u16x8 z = {0, 0, 0, 0, 0, 0, 0, 0};
  *(u16x8*)(xpad + ((size_t)(b * 66 + row) * 66 + col) * 512 + chunk * 8) = z;
}

// ---------- 5b. xpad[b][h+1][wcol+1][i] = bf16(x[b][i][h][wcol])   (NCHW -> padded NHWC)
__global__ void fill_k(const float* __restrict__ x, u16* __restrict__ xpad) {
  const int blk = blockIdx.x;               // 8*64*4 = 2048
  const int ib = blk & 3, hh = (blk >> 2) & 63, b = blk >> 8;
  __shared__ float lx[128][65];
  const int tid = threadIdx.x;
#pragma unroll
  for (int k = 0; k < 2; ++k) {
    const int u = tid + k * 256;
    const int i = u >> 2, w0 = (u & 3) * 16;
    const float* src = x + (size_t)((b * 512 + ib * 128 + i) * 64 + hh) * 64 + w0;
    float tmp[16];
    ((float4*)tmp)[0] = ((const float4*)src)[0];
    ((float4*)tmp)[1] = ((const float4*)src)[1];
    ((float4*)tmp)[2] = ((const float4*)src)[2];
    ((float4*)tmp)[3] = ((const float4*)src)[3];
#pragma unroll
    for (int j = 0; j < 16; ++j) lx[i][w0 + j] = tmp[j];
  }
  __syncthreads();
  const int c = tid >> 2, q = tid & 3;      // c: 0..63 col, q: i-subgroup
  const size_t base = ((size_t)(b * 66 + hh + 1) * 66 + (c + 1)) * 512 + ib * 128;
#pragma unroll
  for (int k = 0; k < 4; ++k) {
    const int irow = k * 32 + q * 8;
    u16x8 pk;
#pragma unroll
    for (int j = 0; j < 8; ++j) pk[j] = f2bf(lx[irow + j][c]);
    *(u16x8*)(xpad + base + irow) = pk;
  }
}

// ---------- 6. conv: out[b][o][h][w] = sum_{t,i} xpad[b][h+ty][w+tx][i] * ww[b][t][o][i]
// block: 64 o x [8 rows x 64 px], 4 waves; wave = 64o x 128px (2 rows) -> reads/MFMA = 0.375
// LDS: WS [9][64 o][32 i] (36864B) + XS [10 rows][66 col][32 i] (42240B) = 79104B, 2 blk/CU
// 16B-chunk XOR swizzle per region: phys = log ^ ((log>>3)&3) (involution), source-side
// pre-swizzled for global_load_lds (linear dest), read-side same XOR.
__global__ __launch_bounds__(256, 2) void conv_k(const u16* __restrict__ xpad,
                                                 const u16* __restrict__ wwb,
                                                 float* __restrict__ out) {
  __shared__ __align__(1024) char SM[79104];
  int blk = (int)blockIdx.x;
  blk = ((blk & 7) << 6) | (blk >> 3);      // XCD swizzle (512 % 8 == 0, bijective)
  const int pt = blk & 7, ot = (blk >> 3) & 7, b = blk >> 6;
  const int tid = threadIdx.x;
  const int lane = tid & 63, wv = tid >> 6;
  const int rA = lane >> 4, cA = lane & 15;
  const int h0 = pt * 8;

  const size_t wwbase = (size_t)(b * 9) * 262144 + (size_t)ot * 64 * 512;
  const size_t xbase  = (size_t)(b * 66 + h0) * (66 * 512);

  // -------- per-thread staging pointers (advance 64B per kb) --------
  const u16* aw[9];  char* dw[9];
  const u16* ax[11]; char* dx[11];
#pragma unroll
  for (int r = 0; r < 9; ++r) {
    const int cc = tid + r * 256;                 // linear LDS dest chunk
    const int lc = cc ^ ((cc >> 3) & 3);          // logical chunk at this slot
    const int i8 = lc & 3, o = (lc >> 2) & 63, t = lc >> 8;
    aw[r] = wwb + wwbase + (size_t)t * 262144 + o * 512 + i8 * 8;
    dw[r] = SM + cc * 16;
  }
#pragma unroll
  for (int r = 0; r < 11; ++r) {
    const int c2 = tid + r * 256;
    const int lc = c2 ^ ((c2 >> 3) & 3);
    const int i8 = lc & 3, rc = lc >> 2;          // rc = row*66+col -> offset rc*512
    ax[r] = xpad + xbase + (size_t)rc * 512 + i8 * 8;
    dx[r] = SM + 36864 + c2 * 16;
  }
  const bool extra = (tid < 80);                  // 2640 = 10*256 + 80

  f32x4 acc[4][8];
#pragma unroll
  for (int i = 0; i < 4; ++i)
#pragma unroll
    for (int j = 0; j < 8; ++j) acc[i][j] = (f32x4){0.f, 0.f, 0.f, 0.f};

  const char* Ab = SM + ((cA * 64 + rA * 16) ^ ((cA << 3) & 0x30));

  for (int kb = 0; kb < 16; ++kb) {
#pragma unroll
    for (int r = 0; r < 9; ++r) gload16(aw[r], dw[r]);
#pragma unroll
    for (int r = 0; r < 10; ++r) gload16(ax[r], dx[r]);
    if (extra) gload16(ax[10], dx[10]);
    asm volatile("s_waitcnt vmcnt(0)" ::: "memory");
    __syncthreads();

#pragma unroll
    for (int t = 0; t < 9; ++t) {
      const int ty = t / 3, tx = t % 3;
      bf16x8 af[4];
#pragma unroll
      for (int mi = 0; mi < 4; ++mi)
        af[mi] = *(const bf16x8*)(Ab + t * 4096 + mi * 1024);
#pragma unroll
      for (int hf = 0; hf < 2; ++hf) {
        const int rct = (2 * wv + ty + hf) * 66 + cA + tx;
        const char* Bt = SM + 36864 + ((rct * 64 + rA * 16) ^ ((rct << 3) & 0x30));
        bf16x8 bfr[4];
#pragma unroll
        for (int n = 0; n < 4; ++n)
          bfr[n] = *(const bf16x8*)(Bt + n * 1024);   // +16 cols: untouched swz bits
#pragma unroll
        for (int mi = 0; mi < 4; ++mi)
#pragma unroll
          for (int n = 0; n < 4; ++n)
            acc[mi][hf * 4 + n] = __builtin_amdgcn_mfma_f32_16x16x32_bf16(
                af[mi], bfr[n], acc[mi][hf * 4 + n], 0, 0, 0);
      }
    }
    __syncthreads();

#pragma unroll
    for (int r = 0; r < 9; ++r) aw[r] += 32;      // +64B: next i-chunk
#pragma unroll
    for (int r = 0; r < 11; ++r) ax[r] += 32;
  }

  const int hb = h0 + 2 * wv;
#pragma unroll
  for (int mi = 0; mi < 4; ++mi)
#pragma unroll
    for (int ni = 0; ni < 8; ++ni) {
      const int h = hb + (ni >> 2);
      const int wc = (ni & 3) * 16 + cA;
#pragma unroll
      for (int r = 0; r < 4; ++r) {
        const int o = ot * 64 + mi * 16 + rA * 4 + r;
        out[((size_t)(b * 512 + o) * 64 + h) * 64 + wc] = acc[mi][ni][r];
      }
    }
}

extern "C" void kernel_launch(void* const* d_in, const int* in_sizes, int n_in,
                              void* d_out, int out_size, void* d_ws, size_t ws_size,
                              hipStream_t stream) {
  const float* x     = (const float*)d_in[0];   // [8,512,64,64]
  const float* y     = (const float*)d_in[1];   // [8,512]
  const float* w     = (const float*)d_in[2];   // [3,3,512,512]
  const float* w_mod = (const float*)d_in[3];   // [512,512]
  const float* b_mod = (const float*)d_in[4];   // [512]
  float* out = (float*)d_out;

  char* ws = (char*)d_ws;
  float* s    = (float*)(ws);                               // 16 KB
  float* dmd  = (float*)(ws + 16384);                       // 16 KB
  float* wsq  = (float*)(ws + 32768);                       // 1 MB
  u16*   wwb  = (u16*)(ws + 32768 + 1048576);               // 37,748,736 B
  u16*   xpad = (u16*)(ws + 32768 + 1048576 + 37748736);    // 35,684,352 B

  style_k<<<64, 256, 0, stream>>>(y, w_mod, b_mod, s);
  wsq_k<<<1024, 256, 0, stream>>>(w, wsq);
  demod_k<<<64, 256, 0, stream>>>(s, wsq, dmd);
  modw_k<<<1152, 256, 0, stream>>>(w, s, dmd, wwb);
  border_k<<<520, 256, 0, stream>>>(xpad);
  fill_k<<<2048, 256, 0, stream>>>(x, xpad);
  conv_k<<<512, 256, 0, stream>>>(xpad, wwb, out);
}